// Round 1
// baseline (8380.208 us; speedup 1.0000x reference)
//
#include <hip/hip_runtime.h>
#include <math.h>

static inline int div_up(long long a, long long b) { return (int)((a + b - 1) / b); }

// ---------------- degree / normalization ----------------

__global__ void k_deg_init(float* __restrict__ deg, int N) {
    int i = blockIdx.x * blockDim.x + threadIdx.x;
    if (i < N) deg[i] = 1.0f;   // self-loop contributes 1
}

__global__ void k_deg_acc(const int* __restrict__ dst, float* __restrict__ deg, int E) {
    int i = blockIdx.x * blockDim.x + threadIdx.x;
    int stride = gridDim.x * blockDim.x;
    for (; i < E; i += stride) atomicAdd(&deg[dst[i]], 1.0f);
}

__global__ void k_dis(float* __restrict__ deg, int N) {
    int i = blockIdx.x * blockDim.x + threadIdx.x;
    if (i < N) deg[i] = rsqrtf(deg[i]);   // deg >= 1 always (self-loop)
}

// ---------------- propagation: h_out = A_hat_norm @ h_in ----------------

// Self-loop term: h_out[i] = dis[i]^2 * h_in[i]  (full overwrite -> no memset)
template<int F>
__global__ void k_prop_init(const float* __restrict__ hin, const float* __restrict__ dis,
                            float* __restrict__ hout, int N) {
    int t = blockIdx.x * blockDim.x + threadIdx.x;
    int total = N * (F / 4);
    if (t >= total) return;
    int n = t / (F / 4);
    float w = dis[n];
    w = w * w;
    float4 v = reinterpret_cast<const float4*>(hin)[t];
    v.x *= w; v.y *= w; v.z *= w; v.w *= w;
    reinterpret_cast<float4*>(hout)[t] = v;
}

// Edge term: h_out[dst] += dis[src]*dis[dst] * h_in[src]
// TPE = F/4 lanes per edge, each lane moves one float4.
template<int F>
__global__ void k_prop_edges(const int* __restrict__ src, const int* __restrict__ dst,
                             const float* __restrict__ dis,
                             const float* __restrict__ hin, float* __restrict__ hout,
                             int E) {
    constexpr int TPE = F / 4;
    int t = blockIdx.x * blockDim.x + threadIdx.x;
    int e = t / TPE;
    if (e >= E) return;
    int l = t % TPE;
    int s = src[e], d = dst[e];
    float w = dis[s] * dis[d];
    float4 v = *reinterpret_cast<const float4*>(hin + (size_t)s * F + 4 * l);
    float* o = hout + (size_t)d * F + 4 * l;
    atomicAdd(o + 0, w * v.x);
    atomicAdd(o + 1, w * v.y);
    atomicAdd(o + 2, w * v.z);
    atomicAdd(o + 3, w * v.w);
}

// ---------------- dense layers ----------------

// Y[n,h] = relu( X[n,:128] @ W[:,h] + b[h] ),  block = 4 nodes x 64 outputs
__global__ void k_gemm_relu_128_64(const float* __restrict__ X, const float* __restrict__ W,
                                   const float* __restrict__ b, float* __restrict__ Y, int N) {
    __shared__ float sx[4][128];
    int node0 = blockIdx.x * 4;
    int tid = threadIdx.x;
    for (int i = tid; i < 4 * 128; i += 256) {
        int n = node0 + i / 128;
        sx[i / 128][i % 128] = (n < N) ? X[(size_t)n * 128 + (i % 128)] : 0.0f;
    }
    __syncthreads();
    int ln = tid >> 6;        // local node (one wave per node)
    int h  = tid & 63;
    int n = node0 + ln;
    if (n >= N) return;
    float acc = b[h];
#pragma unroll 8
    for (int k = 0; k < 128; ++k) acc += sx[ln][k] * W[k * 64 + h];
    Y[(size_t)n * 64 + h] = fmaxf(acc, 0.0f);
}

// Y[n,c] = log_softmax( X[n,:64] @ W[:,c] + b[c] ); one wave per node, lanes>=40 padded.
__global__ void k_gemm_lsm_64_40(const float* __restrict__ X, const float* __restrict__ W,
                                 const float* __restrict__ b, float* __restrict__ Y, int N) {
    int gid = blockIdx.x * blockDim.x + threadIdx.x;
    int node = gid >> 6;
    int lane = threadIdx.x & 63;
    if (node >= N) return;
    const float* xr = X + (size_t)node * 64;
    float acc;
    if (lane < 40) {
        acc = b[lane];
#pragma unroll 8
        for (int k = 0; k < 64; ++k) acc += xr[k] * W[k * 40 + lane];
    } else {
        acc = -INFINITY;
    }
    float m = acc;
    for (int off = 32; off >= 1; off >>= 1) m = fmaxf(m, __shfl_xor(m, off));
    float ev = (lane < 40) ? expf(acc - m) : 0.0f;
    float s = ev;
    for (int off = 32; off >= 1; off >>= 1) s += __shfl_xor(s, off);
    if (lane < 40) Y[(size_t)node * 40 + lane] = acc - m - logf(s);
}

// ---------------- launch ----------------

extern "C" void kernel_launch(void* const* d_in, const int* in_sizes, int n_in,
                              void* d_out, int out_size, void* d_ws, size_t ws_size,
                              hipStream_t stream) {
    const float* x  = (const float*)d_in[0];
    const int*   ei = (const int*)d_in[1];
    const float* W1 = (const float*)d_in[2];
    const float* b1 = (const float*)d_in[3];
    const float* W2 = (const float*)d_in[4];
    const float* b2 = (const float*)d_in[5];
    float* out = (float*)d_out;

    const int H = in_sizes[3];            // 64
    const int C = in_sizes[5];            // 40
    const int F = in_sizes[2] / H;        // 128
    const int N = in_sizes[0] / F;        // 100000
    const int E = in_sizes[1] / 2;        // 1600000
    (void)C; (void)ws_size;

    const int* src = ei;
    const int* dst = ei + E;

    // workspace layout
    float* dis  = (float*)d_ws;                         // N (padded to 256)
    float* bufA = dis + ((N + 255) & ~255);             // N*F
    float* bufB = bufA + (size_t)N * F;                 // N*F

    const int B = 256;

    // deg -> dis
    k_deg_init<<<div_up(N, B), B, 0, stream>>>(dis, N);
    k_deg_acc<<<div_up(E, B * 8), B, 0, stream>>>(dst, dis, E);
    k_dis<<<div_up(N, B), B, 0, stream>>>(dis, N);

    // ---- layer 1: two propagation rounds at F=128 ----
    k_prop_init<128><<<div_up((long long)N * 32, B), B, 0, stream>>>(x, dis, bufA, N);
    k_prop_edges<128><<<div_up((long long)E * 32, B), B, 0, stream>>>(src, dst, dis, x, bufA, E);

    k_prop_init<128><<<div_up((long long)N * 32, B), B, 0, stream>>>(bufA, dis, bufB, N);
    k_prop_edges<128><<<div_up((long long)E * 32, B), B, 0, stream>>>(src, dst, dis, bufA, bufB, E);

    // gemm1 + relu: bufB (N x 128) -> bufA (N x 64)
    k_gemm_relu_128_64<<<div_up(N, 4), 256, 0, stream>>>(bufB, W1, b1, bufA, N);

    // ---- layer 2: two propagation rounds at F=64 ----
    k_prop_init<64><<<div_up((long long)N * 16, B), B, 0, stream>>>(bufA, dis, bufB, N);
    k_prop_edges<64><<<div_up((long long)E * 16, B), B, 0, stream>>>(src, dst, dis, bufA, bufB, E);

    k_prop_init<64><<<div_up((long long)N * 16, B), B, 0, stream>>>(bufB, dis, bufA, N);
    k_prop_edges<64><<<div_up((long long)E * 16, B), B, 0, stream>>>(src, dst, dis, bufB, bufA, E);

    // gemm2 + log_softmax: bufA (N x 64) -> out (N x 40)
    k_gemm_lsm_64_40<<<div_up(N * 64, 256), 256, 0, stream>>>(bufA, W2, b2, out, N);
}

// Round 2
// 854.290 us; speedup vs baseline: 9.8096x; 9.8096x over previous
//
#include <hip/hip_runtime.h>
#include <math.h>

static inline int div_up(long long a, long long b) { return (int)((a + b - 1) / b); }

// ---------------- CSR build ----------------

__global__ void k_zero_i32(int* __restrict__ p, int n) {
    int i = blockIdx.x * blockDim.x + threadIdx.x;
    if (i < n) p[i] = 0;
}

__global__ void k_cnt(const int* __restrict__ dst, int* __restrict__ cnt, int E) {
    int i = blockIdx.x * blockDim.x + threadIdx.x;
    int stride = gridDim.x * blockDim.x;
    for (; i < E; i += stride) atomicAdd(&cnt[dst[i]], 1);
}

// dis[i] = rsqrt(indeg + 1)   (self-loop contributes 1; always > 0)
__global__ void k_dis(const int* __restrict__ cnt, float* __restrict__ dis, int N) {
    int i = blockIdx.x * blockDim.x + threadIdx.x;
    if (i < N) dis[i] = rsqrtf((float)cnt[i] + 1.0f);
}

// Single-workgroup exclusive scan, 1024 threads x 8 values per iteration.
__global__ void k_scan_excl(const int* __restrict__ cnt, int* __restrict__ rp, int N) {
    __shared__ int wsum[16];
    __shared__ int s_carry;
    const int tid = threadIdx.x;
    const int lane = tid & 63, wid = tid >> 6;
    if (tid == 0) s_carry = 0;
    __syncthreads();
    for (int base = 0; base < N; base += 1024 * 8) {
        int i0 = base + tid * 8;
        int v[8];
        int t = 0;
#pragma unroll
        for (int j = 0; j < 8; ++j) {
            int idx = i0 + j;
            v[j] = (idx < N) ? cnt[idx] : 0;
            t += v[j];
        }
        int x = t;  // inclusive wave scan
        for (int off = 1; off < 64; off <<= 1) {
            int y = __shfl_up(x, off);
            if (lane >= off) x += y;
        }
        if (lane == 63) wsum[wid] = x;
        __syncthreads();
        if (tid < 16) {
            int s = wsum[tid];
            for (int off = 1; off < 16; off <<= 1) {
                int y = __shfl_up(s, off);
                if (tid >= off) s += y;
            }
            wsum[tid] = s;
        }
        __syncthreads();
        int carry = s_carry;
        int woff = (wid > 0) ? wsum[wid - 1] : 0;
        int run = carry + woff + (x - t);  // exclusive prefix of this thread's first value
#pragma unroll
        for (int j = 0; j < 8; ++j) {
            int idx = i0 + j;
            if (idx < N) rp[idx] = run;
            run += v[j];
        }
        __syncthreads();
        if (tid == 0) s_carry = carry + wsum[15];
        __syncthreads();
    }
    if (tid == 0) rp[N] = s_carry;
}

__global__ void k_copy_i32(const int* __restrict__ a, int* __restrict__ b, int n) {
    int i = blockIdx.x * blockDim.x + threadIdx.x;
    if (i < n) b[i] = a[i];
}

__global__ void k_scatter(const int* __restrict__ src, const int* __restrict__ dst,
                          int* __restrict__ next, int* __restrict__ csrc, int E) {
    int i = blockIdx.x * blockDim.x + threadIdx.x;
    if (i >= E) return;
    int d = dst[i];
    int pos = atomicAdd(&next[d], 1);
    csrc[pos] = src[i];
}

// ---------------- propagation: h_out = A_hat_norm @ h_in (gather form) ----------------

// TPE = F/4 lanes per node; each lane owns one float4 column chunk.
template<int F>
__global__ void k_prop_gather(const int* __restrict__ rp, const int* __restrict__ csrc,
                              const float* __restrict__ dis,
                              const float* __restrict__ hin, float* __restrict__ hout, int N) {
    constexpr int TPE = F / 4;
    int t = blockIdx.x * blockDim.x + threadIdx.x;
    int n = t / TPE;
    if (n >= N) return;
    int l = t % TPE;
    float dn = dis[n];
    float4 acc = *reinterpret_cast<const float4*>(hin + (size_t)n * F + 4 * l);
    float wn = dn * dn;
    acc.x *= wn; acc.y *= wn; acc.z *= wn; acc.w *= wn;
    int e = rp[n], end = rp[n + 1];
    for (; e + 1 < end; e += 2) {
        int s0 = csrc[e], s1 = csrc[e + 1];
        float w0 = dis[s0] * dn, w1 = dis[s1] * dn;
        float4 v0 = *reinterpret_cast<const float4*>(hin + (size_t)s0 * F + 4 * l);
        float4 v1 = *reinterpret_cast<const float4*>(hin + (size_t)s1 * F + 4 * l);
        acc.x += w0 * v0.x + w1 * v1.x;
        acc.y += w0 * v0.y + w1 * v1.y;
        acc.z += w0 * v0.z + w1 * v1.z;
        acc.w += w0 * v0.w + w1 * v1.w;
    }
    if (e < end) {
        int s0 = csrc[e];
        float w0 = dis[s0] * dn;
        float4 v0 = *reinterpret_cast<const float4*>(hin + (size_t)s0 * F + 4 * l);
        acc.x += w0 * v0.x; acc.y += w0 * v0.y; acc.z += w0 * v0.z; acc.w += w0 * v0.w;
    }
    *reinterpret_cast<float4*>(hout + (size_t)n * F + 4 * l) = acc;
}

// ---------------- dense layers ----------------

__global__ void k_gemm_relu_128_64(const float* __restrict__ X, const float* __restrict__ W,
                                   const float* __restrict__ b, float* __restrict__ Y, int N) {
    __shared__ float sx[4][128];
    int node0 = blockIdx.x * 4;
    int tid = threadIdx.x;
    for (int i = tid; i < 4 * 128; i += 256) {
        int n = node0 + i / 128;
        sx[i / 128][i % 128] = (n < N) ? X[(size_t)n * 128 + (i % 128)] : 0.0f;
    }
    __syncthreads();
    int ln = tid >> 6;
    int h  = tid & 63;
    int n = node0 + ln;
    if (n >= N) return;
    float acc = b[h];
#pragma unroll 8
    for (int k = 0; k < 128; ++k) acc += sx[ln][k] * W[k * 64 + h];
    Y[(size_t)n * 64 + h] = fmaxf(acc, 0.0f);
}

__global__ void k_gemm_lsm_64_40(const float* __restrict__ X, const float* __restrict__ W,
                                 const float* __restrict__ b, float* __restrict__ Y, int N) {
    int gid = blockIdx.x * blockDim.x + threadIdx.x;
    int node = gid >> 6;
    int lane = threadIdx.x & 63;
    if (node >= N) return;
    const float* xr = X + (size_t)node * 64;
    float acc;
    if (lane < 40) {
        acc = b[lane];
#pragma unroll 8
        for (int k = 0; k < 64; ++k) acc += xr[k] * W[k * 40 + lane];
    } else {
        acc = -INFINITY;
    }
    float m = acc;
    for (int off = 32; off >= 1; off >>= 1) m = fmaxf(m, __shfl_xor(m, off));
    float ev = (lane < 40) ? expf(acc - m) : 0.0f;
    float s = ev;
    for (int off = 32; off >= 1; off >>= 1) s += __shfl_xor(s, off);
    if (lane < 40) Y[(size_t)node * 40 + lane] = acc - m - logf(s);
}

// ---------------- launch ----------------

extern "C" void kernel_launch(void* const* d_in, const int* in_sizes, int n_in,
                              void* d_out, int out_size, void* d_ws, size_t ws_size,
                              hipStream_t stream) {
    const float* x  = (const float*)d_in[0];
    const int*   ei = (const int*)d_in[1];
    const float* W1 = (const float*)d_in[2];
    const float* b1 = (const float*)d_in[3];
    const float* W2 = (const float*)d_in[4];
    const float* b2 = (const float*)d_in[5];
    float* out = (float*)d_out;

    const int H = in_sizes[3];            // 64
    const int F = in_sizes[2] / H;        // 128
    const int N = in_sizes[0] / F;        // 100000
    const int E = in_sizes[1] / 2;        // 1600000
    (void)ws_size; (void)n_in; (void)out_size;

    const int* src = ei;
    const int* dst = ei + E;

    // workspace layout (all 4-byte elems)
    const int Npad = (N + 256) & ~255;          // covers N+1
    float* dis  = (float*)d_ws;                 // N
    int*   cnt  = (int*)(dis + Npad);           // N   (later reused as scatter cursor)
    int*   rp   = cnt + Npad;                   // N+1
    int*   csrc = rp + Npad;                    // E
    float* bufA = (float*)(csrc + ((E + 255) & ~255));   // N*F
    float* bufB = bufA + (size_t)N * F;                  // N*F

    const int B = 256;

    // ---- CSR build: count -> dis -> scan -> scatter ----
    k_zero_i32<<<div_up(N, B), B, 0, stream>>>(cnt, N);
    k_cnt<<<div_up(E, B * 8), B, 0, stream>>>(dst, cnt, E);
    k_dis<<<div_up(N, B), B, 0, stream>>>(cnt, dis, N);
    k_scan_excl<<<1, 1024, 0, stream>>>(cnt, rp, N);
    k_copy_i32<<<div_up(N, B), B, 0, stream>>>(rp, cnt, N);   // cnt = next cursor
    k_scatter<<<div_up(E, B), B, 0, stream>>>(src, dst, cnt, csrc, E);

    // ---- layer 1: two propagation rounds at F=128 ----
    k_prop_gather<128><<<div_up((long long)N * 32, B), B, 0, stream>>>(rp, csrc, dis, x, bufA, N);
    k_prop_gather<128><<<div_up((long long)N * 32, B), B, 0, stream>>>(rp, csrc, dis, bufA, bufB, N);

    // gemm1 + relu: bufB (N x 128) -> bufA (N x 64)
    k_gemm_relu_128_64<<<div_up(N, 4), 256, 0, stream>>>(bufB, W1, b1, bufA, N);

    // ---- layer 2: two propagation rounds at F=64 ----
    k_prop_gather<64><<<div_up((long long)N * 16, B), B, 0, stream>>>(rp, csrc, dis, bufA, bufB, N);
    k_prop_gather<64><<<div_up((long long)N * 16, B), B, 0, stream>>>(rp, csrc, dis, bufB, bufA, N);

    // gemm2 + log_softmax: bufA (N x 64) -> out (N x 40)
    k_gemm_lsm_64_40<<<div_up((long long)N * 64, 256), 256, 0, stream>>>(bufA, W2, b2, out, N);
}

// Round 3
// 703.265 us; speedup vs baseline: 11.9161x; 1.2147x over previous
//
#include <hip/hip_runtime.h>
#include <math.h>

static inline int div_up(long long a, long long b) { return (int)((a + b - 1) / b); }

// ---------------- CSR build ----------------

__global__ void k_zero_i32(int* __restrict__ p, int n) {
    int i = blockIdx.x * blockDim.x + threadIdx.x;
    if (i < n) p[i] = 0;
}

__global__ void k_cnt(const int* __restrict__ dst, int* __restrict__ cnt, int E) {
    int i = blockIdx.x * blockDim.x + threadIdx.x;
    int stride = gridDim.x * blockDim.x;
    for (; i < E; i += stride) atomicAdd(&cnt[dst[i]], 1);
}

// dis[i] = rsqrt(indeg + 1)   (self-loop contributes 1; always > 0)
__global__ void k_dis(const int* __restrict__ cnt, float* __restrict__ dis, int N) {
    int i = blockIdx.x * blockDim.x + threadIdx.x;
    if (i < N) dis[i] = rsqrtf((float)cnt[i] + 1.0f);
}

// Single-workgroup exclusive scan, 1024 threads x 8 values per iteration.
__global__ void k_scan_excl(const int* __restrict__ cnt, int* __restrict__ rp, int N) {
    __shared__ int wsum[16];
    __shared__ int s_carry;
    const int tid = threadIdx.x;
    const int lane = tid & 63, wid = tid >> 6;
    if (tid == 0) s_carry = 0;
    __syncthreads();
    for (int base = 0; base < N; base += 1024 * 8) {
        int i0 = base + tid * 8;
        int v[8];
        int t = 0;
#pragma unroll
        for (int j = 0; j < 8; ++j) {
            int idx = i0 + j;
            v[j] = (idx < N) ? cnt[idx] : 0;
            t += v[j];
        }
        int x = t;  // inclusive wave scan
        for (int off = 1; off < 64; off <<= 1) {
            int y = __shfl_up(x, off);
            if (lane >= off) x += y;
        }
        if (lane == 63) wsum[wid] = x;
        __syncthreads();
        if (tid < 16) {
            int s = wsum[tid];
            for (int off = 1; off < 16; off <<= 1) {
                int y = __shfl_up(s, off);
                if (tid >= off) s += y;
            }
            wsum[tid] = s;
        }
        __syncthreads();
        int carry = s_carry;
        int woff = (wid > 0) ? wsum[wid - 1] : 0;
        int run = carry + woff + (x - t);
#pragma unroll
        for (int j = 0; j < 8; ++j) {
            int idx = i0 + j;
            if (idx < N) rp[idx] = run;
            run += v[j];
        }
        __syncthreads();
        if (tid == 0) s_carry = carry + wsum[15];
        __syncthreads();
    }
    if (tid == 0) rp[N] = s_carry;
}

__global__ void k_copy_i32(const int* __restrict__ a, int* __restrict__ b, int n) {
    int i = blockIdx.x * blockDim.x + threadIdx.x;
    if (i < n) b[i] = a[i];
}

__global__ void k_scatter(const int* __restrict__ src, const int* __restrict__ dst,
                          int* __restrict__ next, int* __restrict__ csrc, int E) {
    int i = blockIdx.x * blockDim.x + threadIdx.x;
    if (i >= E) return;
    int d = dst[i];
    int pos = atomicAdd(&next[d], 1);
    csrc[pos] = src[i];
}

// ---------------- propagation: h_out = A_hat_norm @ h_in (gather form) ----------------
// TPE = F/4 lanes per node; each lane owns one float4 column chunk. Row stride = F floats.

template<int F>
__global__ void k_prop_gather(const int* __restrict__ rp, const int* __restrict__ csrc,
                              const float* __restrict__ dis,
                              const float* __restrict__ hin, float* __restrict__ hout, int N) {
    constexpr int TPE = F / 4;
    int t = blockIdx.x * blockDim.x + threadIdx.x;
    int n = t / TPE;
    if (n >= N) return;
    int l = t % TPE;
    float dn = dis[n];
    float4 acc = *reinterpret_cast<const float4*>(hin + (size_t)n * F + 4 * l);
    float wn = dn * dn;
    acc.x *= wn; acc.y *= wn; acc.z *= wn; acc.w *= wn;
    int e = rp[n], end = rp[n + 1];
    for (; e + 3 < end; e += 4) {
        int s0 = csrc[e], s1 = csrc[e + 1], s2 = csrc[e + 2], s3 = csrc[e + 3];
        float w0 = dis[s0] * dn, w1 = dis[s1] * dn;
        float w2 = dis[s2] * dn, w3 = dis[s3] * dn;
        float4 v0 = *reinterpret_cast<const float4*>(hin + (size_t)s0 * F + 4 * l);
        float4 v1 = *reinterpret_cast<const float4*>(hin + (size_t)s1 * F + 4 * l);
        float4 v2 = *reinterpret_cast<const float4*>(hin + (size_t)s2 * F + 4 * l);
        float4 v3 = *reinterpret_cast<const float4*>(hin + (size_t)s3 * F + 4 * l);
        acc.x += w0 * v0.x + w1 * v1.x + w2 * v2.x + w3 * v3.x;
        acc.y += w0 * v0.y + w1 * v1.y + w2 * v2.y + w3 * v3.y;
        acc.z += w0 * v0.z + w1 * v1.z + w2 * v2.z + w3 * v3.z;
        acc.w += w0 * v0.w + w1 * v1.w + w2 * v2.w + w3 * v3.w;
    }
    for (; e < end; ++e) {
        int s0 = csrc[e];
        float w0 = dis[s0] * dn;
        float4 v0 = *reinterpret_cast<const float4*>(hin + (size_t)s0 * F + 4 * l);
        acc.x += w0 * v0.x; acc.y += w0 * v0.y; acc.z += w0 * v0.z; acc.w += w0 * v0.w;
    }
    *reinterpret_cast<float4*>(hout + (size_t)n * F + 4 * l) = acc;
}

// ---------------- dense layers ----------------

// Y0[n,h] = X[n,:128] @ W1[:,h]   (no bias, no relu — they move after propagation)
__global__ void k_gemm_128_64(const float* __restrict__ X, const float* __restrict__ W,
                              float* __restrict__ Y, int N) {
    __shared__ float sx[4][128];
    int node0 = blockIdx.x * 4;
    int tid = threadIdx.x;
    for (int i = tid; i < 4 * 128; i += 256) {
        int n = node0 + i / 128;
        sx[i / 128][i % 128] = (n < N) ? X[(size_t)n * 128 + (i % 128)] : 0.0f;
    }
    __syncthreads();
    int ln = tid >> 6;
    int h  = tid & 63;
    int n = node0 + ln;
    if (n >= N) return;
    float acc = 0.0f;
#pragma unroll 8
    for (int k = 0; k < 128; ++k) acc += sx[ln][k] * W[k * 64 + h];
    Y[(size_t)n * 64 + h] = acc;
}

// T[n,c] = sum_k relu(H[n,k] + b1[k]) * W2[k,c]   (N x 64 -> N x 40, packed stride 40)
__global__ void k_relu_gemm_64_40(const float* __restrict__ H, const float* __restrict__ b1,
                                  const float* __restrict__ W2, float* __restrict__ T,
                                  int NC) {
    int t = blockIdx.x * blockDim.x + threadIdx.x;
    if (t >= NC) return;
    int n = t / 40;
    int c = t % 40;
    const float* hr = H + (size_t)n * 64;
    float acc = 0.0f;
#pragma unroll 8
    for (int k = 0; k < 64; ++k) acc += fmaxf(hr[k] + b1[k], 0.0f) * W2[k * 40 + c];
    T[t] = acc;
}

// out[n,c] = log_softmax(T[n,:40] + b2)   one wave per node, lanes >= 40 padded
__global__ void k_bias_lsm(const float* __restrict__ T, const float* __restrict__ b2,
                           float* __restrict__ Y, int N) {
    int gid = blockIdx.x * blockDim.x + threadIdx.x;
    int node = gid >> 6;
    int lane = threadIdx.x & 63;
    if (node >= N) return;
    float v = (lane < 40) ? T[(size_t)node * 40 + lane] + b2[lane] : -INFINITY;
    float m = v;
    for (int off = 32; off >= 1; off >>= 1) m = fmaxf(m, __shfl_xor(m, off));
    float ev = (lane < 40) ? expf(v - m) : 0.0f;
    float s = ev;
    for (int off = 32; off >= 1; off >>= 1) s += __shfl_xor(s, off);
    if (lane < 40) Y[(size_t)node * 40 + lane] = v - m - logf(s);
}

// ---------------- launch ----------------

extern "C" void kernel_launch(void* const* d_in, const int* in_sizes, int n_in,
                              void* d_out, int out_size, void* d_ws, size_t ws_size,
                              hipStream_t stream) {
    const float* x  = (const float*)d_in[0];
    const int*   ei = (const int*)d_in[1];
    const float* W1 = (const float*)d_in[2];
    const float* b1 = (const float*)d_in[3];
    const float* W2 = (const float*)d_in[4];
    const float* b2 = (const float*)d_in[5];
    float* out = (float*)d_out;

    const int H = in_sizes[3];            // 64
    const int F = in_sizes[2] / H;        // 128
    const int N = in_sizes[0] / F;        // 100000
    const int E = in_sizes[1] / 2;        // 1600000
    (void)ws_size; (void)n_in; (void)out_size;

    const int* src = ei;
    const int* dst = ei + E;

    // workspace layout (4-byte elems)
    const int Npad = (N + 256) & ~255;          // covers N+1
    float* dis  = (float*)d_ws;                 // N
    int*   cnt  = (int*)(dis + Npad);           // N   (reused as scatter cursor)
    int*   rp   = cnt + Npad;                   // N+1
    int*   csrc = rp + Npad;                    // E
    float* bufA = (float*)(csrc + ((E + 255) & ~255));   // N*64
    float* bufB = bufA + (size_t)N * 64;                 // N*64

    const int B = 256;

    // ---- CSR build: count -> dis -> scan -> scatter ----
    k_zero_i32<<<div_up(N, B), B, 0, stream>>>(cnt, N);
    k_cnt<<<div_up(E, B * 8), B, 0, stream>>>(dst, cnt, E);
    k_dis<<<div_up(N, B), B, 0, stream>>>(cnt, dis, N);
    k_scan_excl<<<1, 1024, 0, stream>>>(cnt, rp, N);
    k_copy_i32<<<div_up(N, B), B, 0, stream>>>(rp, cnt, N);
    k_scatter<<<div_up(E, B), B, 0, stream>>>(src, dst, cnt, csrc, E);

    // ---- layer 1 (commuted): Y0 = X @ W1, then 2 props at F=64 ----
    k_gemm_128_64<<<div_up(N, 4), 256, 0, stream>>>(x, W1, bufA, N);
    k_prop_gather<64><<<div_up((long long)N * 16, B), B, 0, stream>>>(rp, csrc, dis, bufA, bufB, N);
    k_prop_gather<64><<<div_up((long long)N * 16, B), B, 0, stream>>>(rp, csrc, dis, bufB, bufA, N);

    // ---- layer 2 (commuted): T = relu(h + b1) @ W2, then 2 props at F=40 ----
    k_relu_gemm_64_40<<<div_up((long long)N * 40, B), B, 0, stream>>>(bufA, b1, W2, bufB, N * 40);
    k_prop_gather<40><<<div_up((long long)N * 10, B), B, 0, stream>>>(rp, csrc, dis, bufB, bufA, N);
    k_prop_gather<40><<<div_up((long long)N * 10, B), B, 0, stream>>>(rp, csrc, dis, bufA, bufB, N);

    // ---- epilogue: out = log_softmax(T + b2) ----
    k_bias_lsm<<<div_up((long long)N * 64, 256), 256, 0, stream>>>(bufB, b2, out, N);
}